// Round 6
// baseline (190.253 us; speedup 1.0000x reference)
//
#include <hip/hip_runtime.h>
#include <stdint.h>

// Match XLA: no FMA contraction anywhere in the float math.
#pragma clang fp contract(off)

#define N_ANCH 147456
#define HALF_N 73728u
#define NG 256
#define NBINS 4096
#define CAND_CAP 4096
#define K_POS 128u
#define RPN_BATCH 256u
// JAX >= 0.5.0 defaults jax_threefry_partitionable=True. Flip to 0 if labels mismatch.
#define PARTITIONABLE 1

// ---------------- threefry2x32 (exact JAX schedule) ----------------
struct TFOut { uint32_t x0, x1; };

__host__ __device__ constexpr TFOut threefry2x32(uint32_t k0, uint32_t k1,
                                                 uint32_t c0, uint32_t c1) {
  uint32_t ks[3] = {k0, k1, k0 ^ k1 ^ 0x1BD11BDAu};
  uint32_t x0 = c0 + ks[0];
  uint32_t x1 = c1 + ks[1];
  const uint32_t rotA[4] = {13u, 15u, 26u, 6u};
  const uint32_t rotB[4] = {17u, 29u, 16u, 24u};
#pragma unroll
  for (int g = 0; g < 5; ++g) {
#pragma unroll
    for (int r = 0; r < 4; ++r) {
      uint32_t ro = ((g & 1) == 0) ? rotA[r] : rotB[r];
      x0 += x1;
      x1 = (x1 << ro) | (x1 >> (32u - ro));
      x1 ^= x0;
    }
    x0 += ks[(g + 1) % 3];
    x1 += ks[(g + 2) % 3] + (uint32_t)(g + 1);
  }
  return TFOut{x0, x1};
}

// key(42) = [0,42]; split -> kpos, kneg (computed at compile time)
#if PARTITIONABLE
// split: key_i = threefry(key, hi=0, lo=i)
constexpr TFOut SK0 = threefry2x32(0u, 42u, 0u, 0u);
constexpr TFOut SK1 = threefry2x32(0u, 42u, 0u, 1u);
constexpr uint32_t KPOS0 = SK0.x0, KPOS1 = SK0.x1;
constexpr uint32_t KNEG0 = SK1.x0, KNEG1 = SK1.x1;
#else
// original split: counts=[0,1,2,3]; pairs (0,2),(1,3); reshape(2,2)
constexpr TFOut SA = threefry2x32(0u, 42u, 0u, 2u);
constexpr TFOut SB = threefry2x32(0u, 42u, 1u, 3u);
constexpr uint32_t KPOS0 = SA.x0, KPOS1 = SB.x0;
constexpr uint32_t KNEG0 = SA.x1, KNEG1 = SB.x1;
#endif

// 23-bit mantissa bits of uniform(key, (N,)) element i. Ordering of u is the
// ordering of these 23 bits (u = bitcast(m|0x3F800000)-1 is monotone in m).
__device__ __forceinline__ uint32_t rand_m23(uint32_t k0, uint32_t k1, uint32_t i) {
#if PARTITIONABLE
  TFOut o = threefry2x32(k0, k1, 0u, i);       // counter64 = i -> (hi,lo)=(0,i)
  return (o.x0 ^ o.x1) >> 9;
#else
  uint32_t lo = (i < HALF_N) ? i : i - HALF_N; // counter pair (p, p+HALF)
  TFOut o = threefry2x32(k0, k1, lo, lo + HALF_N);
  return ((i < HALF_N) ? o.x0 : o.x1) >> 9;
#endif
}

// ---------------- anchors ----------------
__device__ const float c_base[9][4] = {
  { -84.f,  -40.f,  99.f,  55.f}, {-176.f,  -88.f, 191.f, 103.f},
  {-360.f, -184.f, 375.f, 199.f}, { -56.f,  -56.f,  71.f,  71.f},
  {-120.f, -120.f, 135.f, 135.f}, {-248.f, -248.f, 263.f, 263.f},
  { -36.f,  -80.f,  51.f,  95.f}, { -80.f, -168.f,  95.f, 183.f},
  {-168.f, -344.f, 183.f, 359.f}
};

__device__ __forceinline__ void anchor_coords(int a, float* x1, float* y1,
                                              float* x2, float* y2) {
  int b = a % 9;
  int cell = a / 9;
  float sx = (float)((cell & 127) << 4);   // (cell % 128) * 16
  float sy = (float)((cell >> 7) << 4);    // (cell / 128) * 16
  *x1 = c_base[b][0] + sx;
  *y1 = c_base[b][1] + sy;
  *x2 = c_base[b][2] + sx;
  *y2 = c_base[b][3] + sy;
}

// ---------------- K1: per-anchor max/argmax IoU, labels, targets ----------------
__global__ __launch_bounds__(256) void k_anchor(const float* __restrict__ gt,
                                                float* __restrict__ labels,
                                                float* __restrict__ targets) {
  __shared__ float4 s_gt[NG];
  __shared__ float s_area[NG];
  const int tid = threadIdx.x;
  float4 bb = ((const float4*)gt)[tid];
  s_gt[tid] = bb;
  s_area[tid] = (bb.z - bb.x + 1.0f) * (bb.w - bb.y + 1.0f);
  __syncthreads();
  const int a = blockIdx.x * 256 + tid;
  float ax1, ay1, ax2, ay2;
  anchor_coords(a, &ax1, &ay1, &ax2, &ay2);
  const float area_a = (ax2 - ax1 + 1.0f) * (ay2 - ay1 + 1.0f);
  float best = -1.0f;
  int bj = 0;
  for (int j = 0; j < NG; ++j) {
    float4 b = s_gt[j];
    float iw = fminf(ax2, b.z) - fmaxf(ax1, b.x) + 1.0f;
    iw = fmaxf(iw, 0.0f);
    float ih = fminf(ay2, b.w) - fmaxf(ay1, b.y) + 1.0f;
    ih = fmaxf(ih, 0.0f);
    float inter = iw * ih;
    float v = inter / (area_a + s_area[j] - inter);
    if (v > best) { best = v; bj = j; }   // first-occurrence argmax
  }
  labels[a] = (best >= 0.7f) ? 1.0f : ((best < 0.3f) ? 0.0f : -1.0f);
  float4 g = s_gt[bj];
  float ew = ax2 - ax1 + 1.0f;
  float eh = ay2 - ay1 + 1.0f;
  float ecx = ax1 + 0.5f * ew;
  float ecy = ay1 + 0.5f * eh;
  float gw = g.z - g.x + 1.0f;
  float gh = g.w - g.y + 1.0f;
  float gcx = g.x + 0.5f * gw;
  float gcy = g.y + 0.5f * gh;
  float4 t;
  t.x = (gcx - ecx) / ew;
  t.y = (gcy - ecy) / eh;
  t.z = logf(gw / ew);
  t.w = logf(gh / eh);
  ((float4*)targets)[a] = t;
}

// ---------------- K2: per-gt argmax anchor -> label = 1 ----------------
__global__ __launch_bounds__(1024) void k_gtbest(const float* __restrict__ gt,
                                                 float* __restrict__ labels) {
  const int j = blockIdx.x;
  const int tid = threadIdx.x;
  float4 b = ((const float4*)gt)[j];
  float area_b = (b.z - b.x + 1.0f) * (b.w - b.y + 1.0f);
  unsigned long long best = 0ull;
  for (int a = tid; a < N_ANCH; a += 1024) {
    float ax1, ay1, ax2, ay2;
    anchor_coords(a, &ax1, &ay1, &ax2, &ay2);
    float area_a = (ax2 - ax1 + 1.0f) * (ay2 - ay1 + 1.0f);
    float iw = fminf(ax2, b.z) - fmaxf(ax1, b.x) + 1.0f;
    iw = fmaxf(iw, 0.0f);
    float ih = fminf(ay2, b.w) - fmaxf(ay1, b.y) + 1.0f;
    ih = fmaxf(ih, 0.0f);
    float inter = iw * ih;
    float v = inter / (area_a + area_b - inter);
    // pack: larger iou wins; ties -> smaller anchor index (first occurrence)
    unsigned long long key = ((unsigned long long)__float_as_uint(v) << 32)
                           | (unsigned long long)(0xFFFFFFFFu - (uint32_t)a);
    if (key > best) best = key;
  }
  __shared__ unsigned long long s_red[1024];
  s_red[tid] = best;
  __syncthreads();
  for (int s = 512; s > 0; s >>= 1) {
    if (tid < s) {
      unsigned long long o = s_red[tid + s];
      if (o > s_red[tid]) s_red[tid] = o;
    }
    __syncthreads();
  }
  if (tid == 0) {
    int besta = (int)(0xFFFFFFFFu - (uint32_t)(s_red[0] & 0xFFFFFFFFull));
    labels[besta] = 1.0f;
  }
}

// ---------------- K3: histograms of random priority (top 12 of 23 bits) ----------------
__global__ __launch_bounds__(256) void k_hist(const float* __restrict__ labels,
                                              uint32_t* __restrict__ hp,
                                              uint32_t* __restrict__ hn) {
  const int a = blockIdx.x * 256 + threadIdx.x;
  float l = labels[a];
  if (l == 1.0f) {
    atomicAdd(&hp[rand_m23(KPOS0, KPOS1, (uint32_t)a) >> 11], 1u);
  } else if (l == 0.0f) {
    atomicAdd(&hn[rand_m23(KNEG0, KNEG1, (uint32_t)a) >> 11], 1u);
  }
}

// ctrl layout (uint32 idx): 0 pos_active, 1 pos_bin, 2 pos_need, 3 cand_pos_cnt,
//                           4 neg_active, 5 neg_bin, 6 neg_need, 7 cand_neg_cnt
// (u64 idx): 4 cutoff_pos (byte 32), 5 cutoff_neg (byte 40). memset-0 => keep-all.
__global__ __launch_bounds__(1024) void k_findbin(const uint32_t* __restrict__ hp,
                                                  const uint32_t* __restrict__ hn,
                                                  uint32_t* __restrict__ ctrl) {
  __shared__ uint32_t s_h[NBINS];
  __shared__ uint32_t s_c[64];
  __shared__ uint32_t s_kneg;
  const int tid = threadIdx.x;

  // ---- positives, K = 128 ----
  for (int i = tid; i < NBINS; i += 1024) s_h[i] = hp[i];
  __syncthreads();
  if (tid < 64) {
    uint32_t s = 0;
    for (int i = 0; i < 64; ++i) s += s_h[tid * 64 + i];
    s_c[tid] = s;
  }
  __syncthreads();
  if (tid == 0) {
    uint32_t total = 0;
    for (int i = 0; i < 64; ++i) total += s_c[i];
    if (total <= K_POS) {
      ctrl[0] = 0u;                      // keep all positives
      s_kneg = RPN_BATCH - total;        // num_bg = 256 - P
    } else {
      uint32_t cum = 0; int ch, bb;
      for (ch = 63; ch >= 0; --ch) { if (cum + s_c[ch] >= K_POS) break; cum += s_c[ch]; }
      for (bb = ch * 64 + 63; bb >= ch * 64; --bb) { if (cum + s_h[bb] >= K_POS) break; cum += s_h[bb]; }
      ctrl[0] = 1u; ctrl[1] = (uint32_t)bb; ctrl[2] = K_POS - cum;
      s_kneg = RPN_BATCH - K_POS;        // 128
    }
  }
  __syncthreads();
  // ---- negatives, K = s_kneg ----
  for (int i = tid; i < NBINS; i += 1024) s_h[i] = hn[i];
  __syncthreads();
  if (tid < 64) {
    uint32_t s = 0;
    for (int i = 0; i < 64; ++i) s += s_h[tid * 64 + i];
    s_c[tid] = s;
  }
  __syncthreads();
  if (tid == 0) {
    uint32_t total = 0;
    for (int i = 0; i < 64; ++i) total += s_c[i];
    uint32_t K = s_kneg;
    if (K == 0u) {
      ctrl[4] = 0u;
      ((unsigned long long*)ctrl)[5] = ~0ull;  // drop all negatives
    } else if (total <= K) {
      ctrl[4] = 0u;                            // keep all negatives
    } else {
      uint32_t cum = 0; int ch, bb;
      for (ch = 63; ch >= 0; --ch) { if (cum + s_c[ch] >= K) break; cum += s_c[ch]; }
      for (bb = ch * 64 + 63; bb >= ch * 64; --bb) { if (cum + s_h[bb] >= K) break; cum += s_h[bb]; }
      ctrl[4] = 1u; ctrl[5] = (uint32_t)bb; ctrl[6] = K - cum;
    }
  }
}

// ---------------- K5: collect threshold-bin candidates ----------------
__global__ __launch_bounds__(256) void k_collect(const float* __restrict__ labels,
                                                 uint32_t* __restrict__ ctrl,
                                                 unsigned long long* __restrict__ cp,
                                                 unsigned long long* __restrict__ cn) {
  const int a = blockIdx.x * 256 + threadIdx.x;
  float l = labels[a];
  if (l == 1.0f) {
    if (ctrl[0]) {
      uint32_t m = rand_m23(KPOS0, KPOS1, (uint32_t)a);
      if ((m >> 11) == ctrl[1]) {
        uint32_t i = atomicAdd(&ctrl[3], 1u);
        if (i < CAND_CAP)
          cp[i] = ((unsigned long long)m << 32) | (unsigned long long)(0xFFFFFFFFu - (uint32_t)a);
      }
    }
  } else if (l == 0.0f) {
    if (ctrl[4]) {
      uint32_t m = rand_m23(KNEG0, KNEG1, (uint32_t)a);
      if ((m >> 11) == ctrl[5]) {
        uint32_t i = atomicAdd(&ctrl[7], 1u);
        if (i < CAND_CAP)
          cn[i] = ((unsigned long long)m << 32) | (unsigned long long)(0xFFFFFFFFu - (uint32_t)a);
      }
    }
  }
}

// ---------------- K6: exact cutoff key among candidates ----------------
__global__ __launch_bounds__(1024) void k_cutoff(uint32_t* __restrict__ ctrl,
                                                 const unsigned long long* __restrict__ cp,
                                                 const unsigned long long* __restrict__ cn) {
  __shared__ unsigned long long s_k[CAND_CAP];
  __shared__ unsigned long long s_m[1024];
  const int tid = threadIdx.x;
  for (int phase = 0; phase < 2; ++phase) {
    uint32_t active = ctrl[phase ? 4 : 0];   // uniform across block
    if (!active) continue;
    uint32_t c = ctrl[phase ? 7 : 3];
    if (c > CAND_CAP) c = CAND_CAP;
    uint32_t need = ctrl[phase ? 6 : 2];
    const unsigned long long* cand = phase ? cn : cp;
    for (uint32_t i = tid; i < c; i += 1024) s_k[i] = cand[i];
    __syncthreads();
    unsigned long long mymin = ~0ull;
    for (uint32_t i = tid; i < c; i += 1024) {
      unsigned long long k = s_k[i];
      uint32_t r = 0;
      for (uint32_t j = 0; j < c; ++j) r += (s_k[j] > k) ? 1u : 0u;
      if (r < need && k < mymin) mymin = k;   // kept candidate, track min key
    }
    s_m[tid] = mymin;
    __syncthreads();
    for (int s = 512; s > 0; s >>= 1) {
      if (tid < s) {
        unsigned long long o = s_m[tid + s];
        if (o < s_m[tid]) s_m[tid] = o;
      }
      __syncthreads();
    }
    if (tid == 0) ((unsigned long long*)ctrl)[4 + phase] = s_m[0];
    __syncthreads();
  }
}

// ---------------- K7: apply subsample drops + inside mask ----------------
__global__ __launch_bounds__(256) void k_apply(float* __restrict__ labels,
                                               const float* __restrict__ meta,
                                               const uint32_t* __restrict__ ctrl) {
  const int a = blockIdx.x * 256 + threadIdx.x;
  float l = labels[a];
  const unsigned long long* cut = (const unsigned long long*)ctrl;
  if (l == 1.0f) {
    unsigned long long key = ((unsigned long long)rand_m23(KPOS0, KPOS1, (uint32_t)a) << 32)
                           | (unsigned long long)(0xFFFFFFFFu - (uint32_t)a);
    if (key < cut[4]) l = -1.0f;
  } else if (l == 0.0f) {
    unsigned long long key = ((unsigned long long)rand_m23(KNEG0, KNEG1, (uint32_t)a) << 32)
                           | (unsigned long long)(0xFFFFFFFFu - (uint32_t)a);
    if (key < cut[5]) l = -1.0f;
  }
  float x1, y1, x2, y2;
  anchor_coords(a, &x1, &y1, &x2, &y2);
  float hh = meta[0], ww = meta[1];
  bool inside = (x1 >= 0.0f) && (y1 >= 0.0f) && (x2 < ww) && (y2 < hh);
  if (!inside) l = -1.0f;
  labels[a] = l;
}

// ---------------- launch ----------------
extern "C" void kernel_launch(void* const* d_in, const int* in_sizes, int n_in,
                              void* d_out, int out_size, void* d_ws, size_t ws_size,
                              hipStream_t stream) {
  (void)in_sizes; (void)n_in; (void)out_size; (void)ws_size;
  const float* gt   = (const float*)d_in[1];
  const float* meta = (const float*)d_in[2];
  float* labels  = (float*)d_out;
  float* targets = labels + N_ANCH;

  uint8_t* ws = (uint8_t*)d_ws;
  uint32_t* hp   = (uint32_t*)(ws);                 // 4096 u32
  uint32_t* hn   = (uint32_t*)(ws + 16384);         // 4096 u32
  uint32_t* ctrl = (uint32_t*)(ws + 32768);         // 128 B (counters + cutoffs)
  unsigned long long* cp = (unsigned long long*)(ws + 32896);          // 32 KB
  unsigned long long* cn = (unsigned long long*)(ws + 32896 + 32768);  // 32 KB
  // total ws use: 98432 bytes

  hipMemsetAsync(d_ws, 0, 32896, stream);  // hists + ctrl (cutoffs default 0 = keep-all)
  k_anchor <<<N_ANCH / 256, 256, 0, stream>>>(gt, labels, targets);
  k_gtbest <<<NG, 1024, 0, stream>>>(gt, labels);
  k_hist   <<<N_ANCH / 256, 256, 0, stream>>>(labels, hp, hn);
  k_findbin<<<1, 1024, 0, stream>>>(hp, hn, ctrl);
  k_collect<<<N_ANCH / 256, 256, 0, stream>>>(labels, ctrl, cp, cn);
  k_cutoff <<<1, 1024, 0, stream>>>(ctrl, cp, cn);
  k_apply  <<<N_ANCH / 256, 256, 0, stream>>>(labels, meta, ctrl);
}

// Round 9
// 128.683 us; speedup vs baseline: 1.4785x; 1.4785x over previous
//
#include <hip/hip_runtime.h>
#include <stdint.h>

// Match XLA: no FMA contraction anywhere in the float math.
#pragma clang fp contract(off)

#define N_ANCH 147456
#define HALF_N 73728u
#define NG 256
#define NBINS 4096
#define CAND_CAP 4096
#define K_POS 128u
#define RPN_BATCH 256u
// Verified round 6: PARTITIONABLE=1 is bit-exact vs the JAX reference.
#define PARTITIONABLE 1

// ---------------- threefry2x32 (exact JAX schedule) ----------------
struct TFOut { uint32_t x0, x1; };

__host__ __device__ constexpr TFOut threefry2x32(uint32_t k0, uint32_t k1,
                                                 uint32_t c0, uint32_t c1) {
  uint32_t ks[3] = {k0, k1, k0 ^ k1 ^ 0x1BD11BDAu};
  uint32_t x0 = c0 + ks[0];
  uint32_t x1 = c1 + ks[1];
  const uint32_t rotA[4] = {13u, 15u, 26u, 6u};
  const uint32_t rotB[4] = {17u, 29u, 16u, 24u};
#pragma unroll
  for (int g = 0; g < 5; ++g) {
#pragma unroll
    for (int r = 0; r < 4; ++r) {
      uint32_t ro = ((g & 1) == 0) ? rotA[r] : rotB[r];
      x0 += x1;
      x1 = (x1 << ro) | (x1 >> (32u - ro));
      x1 ^= x0;
    }
    x0 += ks[(g + 1) % 3];
    x1 += ks[(g + 2) % 3] + (uint32_t)(g + 1);
  }
  return TFOut{x0, x1};
}

// key(42) = [0,42]; split -> kpos, kneg (computed at compile time)
#if PARTITIONABLE
constexpr TFOut SK0 = threefry2x32(0u, 42u, 0u, 0u);
constexpr TFOut SK1 = threefry2x32(0u, 42u, 0u, 1u);
constexpr uint32_t KPOS0 = SK0.x0, KPOS1 = SK0.x1;
constexpr uint32_t KNEG0 = SK1.x0, KNEG1 = SK1.x1;
#else
constexpr TFOut SA = threefry2x32(0u, 42u, 0u, 2u);
constexpr TFOut SB = threefry2x32(0u, 42u, 1u, 3u);
constexpr uint32_t KPOS0 = SA.x0, KPOS1 = SB.x0;
constexpr uint32_t KNEG0 = SA.x1, KNEG1 = SB.x1;
#endif

// 23-bit mantissa bits of uniform(key, (N,)) element i.
__device__ __forceinline__ uint32_t rand_m23(uint32_t k0, uint32_t k1, uint32_t i) {
#if PARTITIONABLE
  TFOut o = threefry2x32(k0, k1, 0u, i);
  return (o.x0 ^ o.x1) >> 9;
#else
  uint32_t lo = (i < HALF_N) ? i : i - HALF_N;
  TFOut o = threefry2x32(k0, k1, lo, lo + HALF_N);
  return ((i < HALF_N) ? o.x0 : o.x1) >> 9;
#endif
}

// ---------------- anchors ----------------
__device__ const float c_base[9][4] = {
  { -84.f,  -40.f,  99.f,  55.f}, {-176.f,  -88.f, 191.f, 103.f},
  {-360.f, -184.f, 375.f, 199.f}, { -56.f,  -56.f,  71.f,  71.f},
  {-120.f, -120.f, 135.f, 135.f}, {-248.f, -248.f, 263.f, 263.f},
  { -36.f,  -80.f,  51.f,  95.f}, { -80.f, -168.f,  95.f, 183.f},
  {-168.f, -344.f, 183.f, 359.f}
};

__device__ __forceinline__ void anchor_coords(int a, float* x1, float* y1,
                                              float* x2, float* y2) {
  int b = a % 9;
  int cell = a / 9;
  float sx = (float)((cell & 127) << 4);
  float sy = (float)((cell >> 7) << 4);
  *x1 = c_base[b][0] + sx;
  *y1 = c_base[b][1] + sy;
  *x2 = c_base[b][2] + sx;
  *y2 = c_base[b][3] + sy;
}

// ---------------- K1: per-anchor max/argmax IoU, labels, targets ----------------
__global__ __launch_bounds__(256) void k_anchor(const float* __restrict__ gt,
                                                float* __restrict__ labels,
                                                float* __restrict__ targets) {
  __shared__ float4 s_gt[NG];
  __shared__ float s_area[NG];
  const int tid = threadIdx.x;
  float4 bb = ((const float4*)gt)[tid];
  s_gt[tid] = bb;
  s_area[tid] = (bb.z - bb.x + 1.0f) * (bb.w - bb.y + 1.0f);
  __syncthreads();
  const int a = blockIdx.x * 256 + tid;
  float ax1, ay1, ax2, ay2;
  anchor_coords(a, &ax1, &ay1, &ax2, &ay2);
  const float area_a = (ax2 - ax1 + 1.0f) * (ay2 - ay1 + 1.0f);
  float best = -1.0f;
  int bj = 0;
  for (int j = 0; j < NG; ++j) {
    float4 b = s_gt[j];
    float iw = fminf(ax2, b.z) - fmaxf(ax1, b.x) + 1.0f;
    iw = fmaxf(iw, 0.0f);
    float ih = fminf(ay2, b.w) - fmaxf(ay1, b.y) + 1.0f;
    ih = fmaxf(ih, 0.0f);
    float inter = iw * ih;
    float v = inter / (area_a + s_area[j] - inter);
    if (v > best) { best = v; bj = j; }   // first-occurrence argmax
  }
  labels[a] = (best >= 0.7f) ? 1.0f : ((best < 0.3f) ? 0.0f : -1.0f);
  float4 g = s_gt[bj];
  float ew = ax2 - ax1 + 1.0f;
  float eh = ay2 - ay1 + 1.0f;
  float ecx = ax1 + 0.5f * ew;
  float ecy = ay1 + 0.5f * eh;
  float gw = g.z - g.x + 1.0f;
  float gh = g.w - g.y + 1.0f;
  float gcx = g.x + 0.5f * gw;
  float gcy = g.y + 0.5f * gh;
  float4 t;
  t.x = (gcx - ecx) / ew;
  t.y = (gcy - ecy) / eh;
  t.z = logf(gw / ew);
  t.w = logf(gh / eh);
  ((float4*)targets)[a] = t;
}

// ---------------- K2: per-gt argmax anchor via separable max (exact) ----------
// Per shape, IoU is monotone in inter = iw(x)*ih(y); the rounded-inter
// maximizer factorizes as {argmax iw} x {argmax ih} (bitwise float max with
// first-occurrence = min position). We pack the IEEE bits of the extent
// (value-monotone for ext >= 0) with the negated position for exact
// tie-breaks, then rebuild iw/ih BIT-IDENTICAL to the full scan's floats.
// Cross-shape winners compared via (iou_bits<<32)|~index, matching the
// reference first-occurrence argmax.
__global__ __launch_bounds__(256) void k_gtbest_sep(const float* __restrict__ gt,
                                                    float* __restrict__ labels) {
  __shared__ unsigned long long s_best[2][9];  // [axis][shape]: (ext_bits<<7)|(127-p)
  __shared__ unsigned long long s_k[9];
  const int j = blockIdx.x;
  const int tid = threadIdx.x;
  if (tid < 18) s_best[tid / 9][tid % 9] = 0ull;
  __syncthreads();
  float4 b = ((const float4*)gt)[j];
  const int axis = tid >> 7;                  // 0: x-sweep, 1: y-sweep
  const int p = tid & 127;
  const float shift = (float)(p << 4);
  const float lo = axis ? b.y : b.x;
  const float hi = axis ? b.w : b.z;
#pragma unroll
  for (int k = 0; k < 9; ++k) {
    const float a1 = c_base[k][axis] + shift;
    const float a2 = c_base[k][axis + 2] + shift;
    float ext = fminf(a2, hi) - fmaxf(a1, lo) + 1.0f;
    ext = fmaxf(ext, 0.0f);                   // same rounding as full scan
    unsigned long long key =
        ((unsigned long long)__float_as_uint(ext) << 7)
      | (unsigned long long)(127 - p);
    atomicMax(&s_best[axis][k], key);         // max ext bits, tie -> min p
  }
  __syncthreads();
  if (tid < 9) {
    const int k = tid;
    unsigned long long kx = s_best[0][k], ky = s_best[1][k];
    float iw = __uint_as_float((uint32_t)(kx >> 7));
    float ih = __uint_as_float((uint32_t)(ky >> 7));
    int xs = 127 - (int)(kx & 127u);
    int ys = 127 - (int)(ky & 127u);
    float inter = iw * ih;
    float area_a = (c_base[k][2] - c_base[k][0] + 1.0f) *
                   (c_base[k][3] - c_base[k][1] + 1.0f);
    float area_b = (b.z - b.x + 1.0f) * (b.w - b.y + 1.0f);
    float v = inter / (area_a + area_b - inter);
    uint32_t a = (uint32_t)((ys * 128 + xs) * 9 + k);
    s_k[k] = ((unsigned long long)__float_as_uint(v) << 32)
           | (unsigned long long)(0xFFFFFFFFu - a);
  }
  __syncthreads();
  if (tid == 0) {
    unsigned long long best = s_k[0];
#pragma unroll
    for (int k = 1; k < 9; ++k) if (s_k[k] > best) best = s_k[k];
    int besta = (int)(0xFFFFFFFFu - (uint32_t)(best & 0xFFFFFFFFull));
    labels[besta] = 1.0f;
  }
}

// ---------------- K3: histograms of random priority (top 12 of 23 bits) ----------------
__global__ __launch_bounds__(256) void k_hist(const float* __restrict__ labels,
                                              uint32_t* __restrict__ hp,
                                              uint32_t* __restrict__ hn) {
  const int a = blockIdx.x * 256 + threadIdx.x;
  float l = labels[a];
  if (l == 1.0f) {
    atomicAdd(&hp[rand_m23(KPOS0, KPOS1, (uint32_t)a) >> 11], 1u);
  } else if (l == 0.0f) {
    atomicAdd(&hn[rand_m23(KNEG0, KNEG1, (uint32_t)a) >> 11], 1u);
  }
}

// ctrl layout (uint32 idx): 0 pos_active, 1 pos_bin, 2 pos_need, 3 cand_pos_cnt,
//                           4 neg_active, 5 neg_bin, 6 neg_need, 7 cand_neg_cnt
// (u64 idx): 4 cutoff_pos (byte 32), 5 cutoff_neg (byte 40). memset-0 => keep-all.
__global__ __launch_bounds__(1024) void k_findbin(const uint32_t* __restrict__ hp,
                                                  const uint32_t* __restrict__ hn,
                                                  uint32_t* __restrict__ ctrl) {
  __shared__ uint32_t s_h[NBINS];
  __shared__ uint32_t s_c[64];
  __shared__ uint32_t s_kneg;
  const int tid = threadIdx.x;

  // ---- positives, K = 128 ----
  for (int i = tid; i < NBINS; i += 1024) s_h[i] = hp[i];
  __syncthreads();
  if (tid < 64) {
    uint32_t s = 0;
    for (int i = 0; i < 64; ++i) s += s_h[tid * 64 + i];
    s_c[tid] = s;
  }
  __syncthreads();
  if (tid == 0) {
    uint32_t total = 0;
    for (int i = 0; i < 64; ++i) total += s_c[i];
    if (total <= K_POS) {
      ctrl[0] = 0u;
      s_kneg = RPN_BATCH - total;
    } else {
      uint32_t cum = 0; int ch, bb;
      for (ch = 63; ch >= 0; --ch) { if (cum + s_c[ch] >= K_POS) break; cum += s_c[ch]; }
      for (bb = ch * 64 + 63; bb >= ch * 64; --bb) { if (cum + s_h[bb] >= K_POS) break; cum += s_h[bb]; }
      ctrl[0] = 1u; ctrl[1] = (uint32_t)bb; ctrl[2] = K_POS - cum;
      s_kneg = RPN_BATCH - K_POS;
    }
  }
  __syncthreads();
  // ---- negatives, K = s_kneg ----
  for (int i = tid; i < NBINS; i += 1024) s_h[i] = hn[i];
  __syncthreads();
  if (tid < 64) {
    uint32_t s = 0;
    for (int i = 0; i < 64; ++i) s += s_h[tid * 64 + i];
    s_c[tid] = s;
  }
  __syncthreads();
  if (tid == 0) {
    uint32_t total = 0;
    for (int i = 0; i < 64; ++i) total += s_c[i];
    uint32_t K = s_kneg;
    if (K == 0u) {
      ctrl[4] = 0u;
      ((unsigned long long*)ctrl)[5] = ~0ull;
    } else if (total <= K) {
      ctrl[4] = 0u;
    } else {
      uint32_t cum = 0; int ch, bb;
      for (ch = 63; ch >= 0; --ch) { if (cum + s_c[ch] >= K) break; cum += s_c[ch]; }
      for (bb = ch * 64 + 63; bb >= ch * 64; --bb) { if (cum + s_h[bb] >= K) break; cum += s_h[bb]; }
      ctrl[4] = 1u; ctrl[5] = (uint32_t)bb; ctrl[6] = K - cum;
    }
  }
}

// ---------------- K5: collect threshold-bin candidates ----------------
__global__ __launch_bounds__(256) void k_collect(const float* __restrict__ labels,
                                                 uint32_t* __restrict__ ctrl,
                                                 unsigned long long* __restrict__ cp,
                                                 unsigned long long* __restrict__ cn) {
  const int a = blockIdx.x * 256 + threadIdx.x;
  float l = labels[a];
  if (l == 1.0f) {
    if (ctrl[0]) {
      uint32_t m = rand_m23(KPOS0, KPOS1, (uint32_t)a);
      if ((m >> 11) == ctrl[1]) {
        uint32_t i = atomicAdd(&ctrl[3], 1u);
        if (i < CAND_CAP)
          cp[i] = ((unsigned long long)m << 32) | (unsigned long long)(0xFFFFFFFFu - (uint32_t)a);
      }
    }
  } else if (l == 0.0f) {
    if (ctrl[4]) {
      uint32_t m = rand_m23(KNEG0, KNEG1, (uint32_t)a);
      if ((m >> 11) == ctrl[5]) {
        uint32_t i = atomicAdd(&ctrl[7], 1u);
        if (i < CAND_CAP)
          cn[i] = ((unsigned long long)m << 32) | (unsigned long long)(0xFFFFFFFFu - (uint32_t)a);
      }
    }
  }
}

// ---------------- K6: exact cutoff key among candidates ----------------
__global__ __launch_bounds__(1024) void k_cutoff(uint32_t* __restrict__ ctrl,
                                                 const unsigned long long* __restrict__ cp,
                                                 const unsigned long long* __restrict__ cn) {
  __shared__ unsigned long long s_k[CAND_CAP];
  __shared__ unsigned long long s_m[1024];
  const int tid = threadIdx.x;
  for (int phase = 0; phase < 2; ++phase) {
    uint32_t active = ctrl[phase ? 4 : 0];
    if (!active) continue;
    uint32_t c = ctrl[phase ? 7 : 3];
    if (c > CAND_CAP) c = CAND_CAP;
    uint32_t need = ctrl[phase ? 6 : 2];
    const unsigned long long* cand = phase ? cn : cp;
    for (uint32_t i = tid; i < c; i += 1024) s_k[i] = cand[i];
    __syncthreads();
    unsigned long long mymin = ~0ull;
    for (uint32_t i = tid; i < c; i += 1024) {
      unsigned long long k = s_k[i];
      uint32_t r = 0;
      for (uint32_t j = 0; j < c; ++j) r += (s_k[j] > k) ? 1u : 0u;
      if (r < need && k < mymin) mymin = k;
    }
    s_m[tid] = mymin;
    __syncthreads();
    for (int s = 512; s > 0; s >>= 1) {
      if (tid < s) {
        unsigned long long o = s_m[tid + s];
        if (o < s_m[tid]) s_m[tid] = o;
      }
      __syncthreads();
    }
    if (tid == 0) ((unsigned long long*)ctrl)[4 + phase] = s_m[0];
    __syncthreads();
  }
}

// ---------------- K7: apply subsample drops + inside mask ----------------
__global__ __launch_bounds__(256) void k_apply(float* __restrict__ labels,
                                               const float* __restrict__ meta,
                                               const uint32_t* __restrict__ ctrl) {
  const int a = blockIdx.x * 256 + threadIdx.x;
  float l = labels[a];
  const unsigned long long* cut = (const unsigned long long*)ctrl;
  if (l == 1.0f) {
    unsigned long long key = ((unsigned long long)rand_m23(KPOS0, KPOS1, (uint32_t)a) << 32)
                           | (unsigned long long)(0xFFFFFFFFu - (uint32_t)a);
    if (key < cut[4]) l = -1.0f;
  } else if (l == 0.0f) {
    unsigned long long key = ((unsigned long long)rand_m23(KNEG0, KNEG1, (uint32_t)a) << 32)
                           | (unsigned long long)(0xFFFFFFFFu - (uint32_t)a);
    if (key < cut[5]) l = -1.0f;
  }
  float x1, y1, x2, y2;
  anchor_coords(a, &x1, &y1, &x2, &y2);
  float hh = meta[0], ww = meta[1];
  bool inside = (x1 >= 0.0f) && (y1 >= 0.0f) && (x2 < ww) && (y2 < hh);
  if (!inside) l = -1.0f;
  labels[a] = l;
}

// ---------------- launch ----------------
extern "C" void kernel_launch(void* const* d_in, const int* in_sizes, int n_in,
                              void* d_out, int out_size, void* d_ws, size_t ws_size,
                              hipStream_t stream) {
  (void)in_sizes; (void)n_in; (void)out_size; (void)ws_size;
  const float* gt   = (const float*)d_in[1];
  const float* meta = (const float*)d_in[2];
  float* labels  = (float*)d_out;
  float* targets = labels + N_ANCH;

  uint8_t* ws = (uint8_t*)d_ws;
  uint32_t* hp   = (uint32_t*)(ws);                 // 4096 u32
  uint32_t* hn   = (uint32_t*)(ws + 16384);         // 4096 u32
  uint32_t* ctrl = (uint32_t*)(ws + 32768);         // 128 B (counters + cutoffs)
  unsigned long long* cp = (unsigned long long*)(ws + 32896);          // 32 KB
  unsigned long long* cn = (unsigned long long*)(ws + 32896 + 32768);  // 32 KB

  hipMemsetAsync(d_ws, 0, 32896, stream);  // hists + ctrl (cutoffs default 0 = keep-all)
  k_anchor     <<<N_ANCH / 256, 256, 0, stream>>>(gt, labels, targets);
  k_gtbest_sep <<<NG, 256, 0, stream>>>(gt, labels);
  k_hist       <<<N_ANCH / 256, 256, 0, stream>>>(labels, hp, hn);
  k_findbin    <<<1, 1024, 0, stream>>>(hp, hn, ctrl);
  k_collect    <<<N_ANCH / 256, 256, 0, stream>>>(labels, ctrl, cp, cn);
  k_cutoff     <<<1, 1024, 0, stream>>>(ctrl, cp, cn);
  k_apply      <<<N_ANCH / 256, 256, 0, stream>>>(labels, meta, ctrl);
}

// Round 10
// 110.085 us; speedup vs baseline: 1.7282x; 1.1689x over previous
//
#include <hip/hip_runtime.h>
#include <stdint.h>

// Match XLA: no FMA contraction anywhere in the float math.
#pragma clang fp contract(off)

#define N_ANCH 147456
#define HALF_N 73728u
#define NG 256
#define NBINS 4096
#define CAND_CAP 4096
#define K_POS 128u
#define RPN_BATCH 256u
// Verified round 6: PARTITIONABLE=1 is bit-exact vs the JAX reference.
#define PARTITIONABLE 1

// ---------------- threefry2x32 (exact JAX schedule) ----------------
struct TFOut { uint32_t x0, x1; };

__host__ __device__ constexpr TFOut threefry2x32(uint32_t k0, uint32_t k1,
                                                 uint32_t c0, uint32_t c1) {
  uint32_t ks[3] = {k0, k1, k0 ^ k1 ^ 0x1BD11BDAu};
  uint32_t x0 = c0 + ks[0];
  uint32_t x1 = c1 + ks[1];
  const uint32_t rotA[4] = {13u, 15u, 26u, 6u};
  const uint32_t rotB[4] = {17u, 29u, 16u, 24u};
#pragma unroll
  for (int g = 0; g < 5; ++g) {
#pragma unroll
    for (int r = 0; r < 4; ++r) {
      uint32_t ro = ((g & 1) == 0) ? rotA[r] : rotB[r];
      x0 += x1;
      x1 = (x1 << ro) | (x1 >> (32u - ro));
      x1 ^= x0;
    }
    x0 += ks[(g + 1) % 3];
    x1 += ks[(g + 2) % 3] + (uint32_t)(g + 1);
  }
  return TFOut{x0, x1};
}

#if PARTITIONABLE
constexpr TFOut SK0 = threefry2x32(0u, 42u, 0u, 0u);
constexpr TFOut SK1 = threefry2x32(0u, 42u, 0u, 1u);
constexpr uint32_t KPOS0 = SK0.x0, KPOS1 = SK0.x1;
constexpr uint32_t KNEG0 = SK1.x0, KNEG1 = SK1.x1;
#else
constexpr TFOut SA = threefry2x32(0u, 42u, 0u, 2u);
constexpr TFOut SB = threefry2x32(0u, 42u, 1u, 3u);
constexpr uint32_t KPOS0 = SA.x0, KPOS1 = SB.x0;
constexpr uint32_t KNEG0 = SA.x1, KNEG1 = SB.x1;
#endif

// 23-bit mantissa bits of uniform(key, (N,)) element i.
__device__ __forceinline__ uint32_t rand_m23(uint32_t k0, uint32_t k1, uint32_t i) {
#if PARTITIONABLE
  TFOut o = threefry2x32(k0, k1, 0u, i);
  return (o.x0 ^ o.x1) >> 9;
#else
  uint32_t lo = (i < HALF_N) ? i : i - HALF_N;
  TFOut o = threefry2x32(k0, k1, lo, lo + HALF_N);
  return ((i < HALF_N) ? o.x0 : o.x1) >> 9;
#endif
}

// ---------------- anchors ----------------
__device__ const float c_base[9][4] = {
  { -84.f,  -40.f,  99.f,  55.f}, {-176.f,  -88.f, 191.f, 103.f},
  {-360.f, -184.f, 375.f, 199.f}, { -56.f,  -56.f,  71.f,  71.f},
  {-120.f, -120.f, 135.f, 135.f}, {-248.f, -248.f, 263.f, 263.f},
  { -36.f,  -80.f,  51.f,  95.f}, { -80.f, -168.f,  95.f, 183.f},
  {-168.f, -344.f, 183.f, 359.f}
};

__device__ __forceinline__ void anchor_coords(int a, float* x1, float* y1,
                                              float* x2, float* y2) {
  int b = a % 9;
  int cell = a / 9;
  float sx = (float)((cell & 127) << 4);
  float sy = (float)((cell >> 7) << 4);
  *x1 = c_base[b][0] + sx;
  *y1 = c_base[b][1] + sy;
  *x2 = c_base[b][2] + sx;
  *y2 = c_base[b][3] + sy;
}

// ---------------- K1: per-anchor argmax IoU, labels, targets, hist ----------
// Packed-key scan: key = (v_bits<<32)|~j; v in [0,1] so float bits are
// value-monotone; ~j gives first-occurrence on ties. 4 independent chains
// break the serial div->cmp dependency; chain0 inits to pack(v=0, j=0) which
// reproduces the reference winner when no gt intersects. inter>0 iff iw>0 and
// ih>0, and skipped pairs contribute exactly v=+0.0 -> skipping the divide is
// bit-exact. Histogram of pre-subsample labels built inline (k_hist deleted);
// k_gtbest_sep repairs the <=256 entries it flips.
__global__ __launch_bounds__(256) void k_anchor(const float* __restrict__ gt,
                                                float* __restrict__ labels,
                                                float* __restrict__ targets,
                                                uint32_t* __restrict__ hp,
                                                uint32_t* __restrict__ hn) {
  __shared__ float4 s_gt[NG];
  __shared__ float s_area[NG];
  const int tid = threadIdx.x;
  float4 bb = ((const float4*)gt)[tid];
  s_gt[tid] = bb;
  s_area[tid] = (bb.z - bb.x + 1.0f) * (bb.w - bb.y + 1.0f);
  __syncthreads();
  const int a = blockIdx.x * 256 + tid;
  float ax1, ay1, ax2, ay2;
  anchor_coords(a, &ax1, &ay1, &ax2, &ay2);
  const float area_a = (ax2 - ax1 + 1.0f) * (ay2 - ay1 + 1.0f);

  unsigned long long c0 = 0x00000000FFFFFFFFull;  // pack(v=0, j=0)
  unsigned long long c1 = 0ull, c2 = 0ull, c3 = 0ull;
#define IOU_STEP(JJ, CH)                                                  \
  {                                                                       \
    float4 b = s_gt[(JJ)];                                                \
    float iw = fminf(ax2, b.z) - fmaxf(ax1, b.x) + 1.0f;                  \
    float ih = fminf(ay2, b.w) - fmaxf(ay1, b.y) + 1.0f;                  \
    if (iw > 0.0f && ih > 0.0f) {                                         \
      float inter = iw * ih;                                              \
      float v = inter / (area_a + s_area[(JJ)] - inter);                  \
      unsigned long long key =                                            \
          ((unsigned long long)__float_as_uint(v) << 32)                  \
        | (unsigned long long)(0xFFFFFFFFu - (uint32_t)(JJ));             \
      if (key > CH) CH = key;                                             \
    }                                                                     \
  }
  for (int j = 0; j < NG; j += 4) {
    IOU_STEP(j + 0, c0)
    IOU_STEP(j + 1, c1)
    IOU_STEP(j + 2, c2)
    IOU_STEP(j + 3, c3)
  }
#undef IOU_STEP
  if (c1 > c0) c0 = c1;
  if (c2 > c0) c0 = c2;
  if (c3 > c0) c0 = c3;
  const float best = __uint_as_float((uint32_t)(c0 >> 32));
  const int bj = (int)(0xFFFFFFFFu - (uint32_t)c0);

  float l = (best >= 0.7f) ? 1.0f : ((best < 0.3f) ? 0.0f : -1.0f);
  labels[a] = l;
  if (l == 1.0f) {
    atomicAdd(&hp[rand_m23(KPOS0, KPOS1, (uint32_t)a) >> 11], 1u);
  } else if (l == 0.0f) {
    atomicAdd(&hn[rand_m23(KNEG0, KNEG1, (uint32_t)a) >> 11], 1u);
  }

  float4 g = s_gt[bj];
  float ew = ax2 - ax1 + 1.0f;
  float eh = ay2 - ay1 + 1.0f;
  float ecx = ax1 + 0.5f * ew;
  float ecy = ay1 + 0.5f * eh;
  float gw = g.z - g.x + 1.0f;
  float gh = g.w - g.y + 1.0f;
  float gcx = g.x + 0.5f * gw;
  float gcy = g.y + 0.5f * gh;
  float4 t;
  t.x = (gcx - ecx) / ew;
  t.y = (gcy - ecy) / eh;
  t.z = logf(gw / ew);
  t.w = logf(gh / eh);
  ((float4*)targets)[a] = t;
}

// ---------------- K2: per-gt argmax anchor via separable max (exact) ----------
// Verified bit-exact round 9. Now also repairs the histograms for flipped
// anchors; atomicExch dedupes when multiple gt share one best anchor.
__global__ __launch_bounds__(256) void k_gtbest_sep(const float* __restrict__ gt,
                                                    float* __restrict__ labels,
                                                    uint32_t* __restrict__ hp,
                                                    uint32_t* __restrict__ hn) {
  __shared__ unsigned long long s_best[2][9];  // [axis][shape]: (ext_bits<<7)|(127-p)
  __shared__ unsigned long long s_k[9];
  const int j = blockIdx.x;
  const int tid = threadIdx.x;
  if (tid < 18) s_best[tid / 9][tid % 9] = 0ull;
  __syncthreads();
  float4 b = ((const float4*)gt)[j];
  const int axis = tid >> 7;                  // 0: x-sweep, 1: y-sweep
  const int p = tid & 127;
  const float shift = (float)(p << 4);
  const float lo = axis ? b.y : b.x;
  const float hi = axis ? b.w : b.z;
#pragma unroll
  for (int k = 0; k < 9; ++k) {
    const float a1 = c_base[k][axis] + shift;
    const float a2 = c_base[k][axis + 2] + shift;
    float ext = fminf(a2, hi) - fmaxf(a1, lo) + 1.0f;
    ext = fmaxf(ext, 0.0f);                   // same rounding as full scan
    unsigned long long key =
        ((unsigned long long)__float_as_uint(ext) << 7)
      | (unsigned long long)(127 - p);
    atomicMax(&s_best[axis][k], key);         // max ext bits, tie -> min p
  }
  __syncthreads();
  if (tid < 9) {
    const int k = tid;
    unsigned long long kx = s_best[0][k], ky = s_best[1][k];
    float iw = __uint_as_float((uint32_t)(kx >> 7));
    float ih = __uint_as_float((uint32_t)(ky >> 7));
    int xs = 127 - (int)(kx & 127u);
    int ys = 127 - (int)(ky & 127u);
    float inter = iw * ih;
    float area_a = (c_base[k][2] - c_base[k][0] + 1.0f) *
                   (c_base[k][3] - c_base[k][1] + 1.0f);
    float area_b = (b.z - b.x + 1.0f) * (b.w - b.y + 1.0f);
    float v = inter / (area_a + area_b - inter);
    uint32_t a = (uint32_t)((ys * 128 + xs) * 9 + k);
    s_k[k] = ((unsigned long long)__float_as_uint(v) << 32)
           | (unsigned long long)(0xFFFFFFFFu - a);
  }
  __syncthreads();
  if (tid == 0) {
    unsigned long long best = s_k[0];
#pragma unroll
    for (int k = 1; k < 9; ++k) if (s_k[k] > best) best = s_k[k];
    uint32_t besta = 0xFFFFFFFFu - (uint32_t)(best & 0xFFFFFFFFull);
    float old = atomicExch(&labels[besta], 1.0f);
    if (old == 0.0f) {
      atomicSub(&hn[rand_m23(KNEG0, KNEG1, besta) >> 11], 1u);
      atomicAdd(&hp[rand_m23(KPOS0, KPOS1, besta) >> 11], 1u);
    } else if (old == -1.0f) {
      atomicAdd(&hp[rand_m23(KPOS0, KPOS1, besta) >> 11], 1u);
    }
  }
}

// ctrl layout (uint32 idx): 0 pos_active, 1 pos_bin, 2 pos_need, 3 cand_pos_cnt,
//                           4 neg_active, 5 neg_bin, 6 neg_need, 7 cand_neg_cnt
// (u64 idx): 4 cutoff_pos (byte 32), 5 cutoff_neg (byte 40). memset-0 => keep-all.
__global__ __launch_bounds__(1024) void k_findbin(const uint32_t* __restrict__ hp,
                                                  const uint32_t* __restrict__ hn,
                                                  uint32_t* __restrict__ ctrl) {
  __shared__ uint32_t s_h[NBINS];
  __shared__ uint32_t s_c[64];
  __shared__ uint32_t s_kneg;
  const int tid = threadIdx.x;

  // ---- positives, K = 128 ----
  for (int i = tid; i < NBINS; i += 1024) s_h[i] = hp[i];
  __syncthreads();
  if (tid < 64) {
    uint32_t s = 0;
    for (int i = 0; i < 64; ++i) s += s_h[tid * 64 + i];
    s_c[tid] = s;
  }
  __syncthreads();
  if (tid == 0) {
    uint32_t total = 0;
    for (int i = 0; i < 64; ++i) total += s_c[i];
    if (total <= K_POS) {
      ctrl[0] = 0u;
      s_kneg = RPN_BATCH - total;
    } else {
      uint32_t cum = 0; int ch, bb;
      for (ch = 63; ch >= 0; --ch) { if (cum + s_c[ch] >= K_POS) break; cum += s_c[ch]; }
      for (bb = ch * 64 + 63; bb >= ch * 64; --bb) { if (cum + s_h[bb] >= K_POS) break; cum += s_h[bb]; }
      ctrl[0] = 1u; ctrl[1] = (uint32_t)bb; ctrl[2] = K_POS - cum;
      s_kneg = RPN_BATCH - K_POS;
    }
  }
  __syncthreads();
  // ---- negatives, K = s_kneg ----
  for (int i = tid; i < NBINS; i += 1024) s_h[i] = hn[i];
  __syncthreads();
  if (tid < 64) {
    uint32_t s = 0;
    for (int i = 0; i < 64; ++i) s += s_h[tid * 64 + i];
    s_c[tid] = s;
  }
  __syncthreads();
  if (tid == 0) {
    uint32_t total = 0;
    for (int i = 0; i < 64; ++i) total += s_c[i];
    uint32_t K = s_kneg;
    if (K == 0u) {
      ctrl[4] = 0u;
      ((unsigned long long*)ctrl)[5] = ~0ull;
    } else if (total <= K) {
      ctrl[4] = 0u;
    } else {
      uint32_t cum = 0; int ch, bb;
      for (ch = 63; ch >= 0; --ch) { if (cum + s_c[ch] >= K) break; cum += s_c[ch]; }
      for (bb = ch * 64 + 63; bb >= ch * 64; --bb) { if (cum + s_h[bb] >= K) break; cum += s_h[bb]; }
      ctrl[4] = 1u; ctrl[5] = (uint32_t)bb; ctrl[6] = K - cum;
    }
  }
}

// ---------------- K5: collect threshold-bin candidates ----------------
__global__ __launch_bounds__(256) void k_collect(const float* __restrict__ labels,
                                                 uint32_t* __restrict__ ctrl,
                                                 unsigned long long* __restrict__ cp,
                                                 unsigned long long* __restrict__ cn) {
  const int a = blockIdx.x * 256 + threadIdx.x;
  float l = labels[a];
  if (l == 1.0f) {
    if (ctrl[0]) {
      uint32_t m = rand_m23(KPOS0, KPOS1, (uint32_t)a);
      if ((m >> 11) == ctrl[1]) {
        uint32_t i = atomicAdd(&ctrl[3], 1u);
        if (i < CAND_CAP)
          cp[i] = ((unsigned long long)m << 32) | (unsigned long long)(0xFFFFFFFFu - (uint32_t)a);
      }
    }
  } else if (l == 0.0f) {
    if (ctrl[4]) {
      uint32_t m = rand_m23(KNEG0, KNEG1, (uint32_t)a);
      if ((m >> 11) == ctrl[5]) {
        uint32_t i = atomicAdd(&ctrl[7], 1u);
        if (i < CAND_CAP)
          cn[i] = ((unsigned long long)m << 32) | (unsigned long long)(0xFFFFFFFFu - (uint32_t)a);
      }
    }
  }
}

// ---------------- K6: exact cutoff key among candidates ----------------
__global__ __launch_bounds__(1024) void k_cutoff(uint32_t* __restrict__ ctrl,
                                                 const unsigned long long* __restrict__ cp,
                                                 const unsigned long long* __restrict__ cn) {
  __shared__ unsigned long long s_k[CAND_CAP];
  __shared__ unsigned long long s_m[1024];
  const int tid = threadIdx.x;
  for (int phase = 0; phase < 2; ++phase) {
    uint32_t active = ctrl[phase ? 4 : 0];
    if (!active) continue;
    uint32_t c = ctrl[phase ? 7 : 3];
    if (c > CAND_CAP) c = CAND_CAP;
    uint32_t need = ctrl[phase ? 6 : 2];
    const unsigned long long* cand = phase ? cn : cp;
    for (uint32_t i = tid; i < c; i += 1024) s_k[i] = cand[i];
    __syncthreads();
    unsigned long long mymin = ~0ull;
    for (uint32_t i = tid; i < c; i += 1024) {
      unsigned long long k = s_k[i];
      uint32_t r = 0;
      for (uint32_t j = 0; j < c; ++j) r += (s_k[j] > k) ? 1u : 0u;
      if (r < need && k < mymin) mymin = k;
    }
    s_m[tid] = mymin;
    __syncthreads();
    for (int s = 512; s > 0; s >>= 1) {
      if (tid < s) {
        unsigned long long o = s_m[tid + s];
        if (o < s_m[tid]) s_m[tid] = o;
      }
      __syncthreads();
    }
    if (tid == 0) ((unsigned long long*)ctrl)[4 + phase] = s_m[0];
    __syncthreads();
  }
}

// ---------------- K7: apply subsample drops + inside mask ----------------
__global__ __launch_bounds__(256) void k_apply(float* __restrict__ labels,
                                               const float* __restrict__ meta,
                                               const uint32_t* __restrict__ ctrl) {
  const int a = blockIdx.x * 256 + threadIdx.x;
  float l = labels[a];
  const unsigned long long* cut = (const unsigned long long*)ctrl;
  if (l == 1.0f) {
    unsigned long long key = ((unsigned long long)rand_m23(KPOS0, KPOS1, (uint32_t)a) << 32)
                           | (unsigned long long)(0xFFFFFFFFu - (uint32_t)a);
    if (key < cut[4]) l = -1.0f;
  } else if (l == 0.0f) {
    unsigned long long key = ((unsigned long long)rand_m23(KNEG0, KNEG1, (uint32_t)a) << 32)
                           | (unsigned long long)(0xFFFFFFFFu - (uint32_t)a);
    if (key < cut[5]) l = -1.0f;
  }
  float x1, y1, x2, y2;
  anchor_coords(a, &x1, &y1, &x2, &y2);
  float hh = meta[0], ww = meta[1];
  bool inside = (x1 >= 0.0f) && (y1 >= 0.0f) && (x2 < ww) && (y2 < hh);
  if (!inside) l = -1.0f;
  labels[a] = l;
}

// ---------------- launch ----------------
extern "C" void kernel_launch(void* const* d_in, const int* in_sizes, int n_in,
                              void* d_out, int out_size, void* d_ws, size_t ws_size,
                              hipStream_t stream) {
  (void)in_sizes; (void)n_in; (void)out_size; (void)ws_size;
  const float* gt   = (const float*)d_in[1];
  const float* meta = (const float*)d_in[2];
  float* labels  = (float*)d_out;
  float* targets = labels + N_ANCH;

  uint8_t* ws = (uint8_t*)d_ws;
  uint32_t* hp   = (uint32_t*)(ws);                 // 4096 u32
  uint32_t* hn   = (uint32_t*)(ws + 16384);         // 4096 u32
  uint32_t* ctrl = (uint32_t*)(ws + 32768);         // 128 B (counters + cutoffs)
  unsigned long long* cp = (unsigned long long*)(ws + 32896);          // 32 KB
  unsigned long long* cn = (unsigned long long*)(ws + 32896 + 32768);  // 32 KB

  hipMemsetAsync(d_ws, 0, 32896, stream);  // hists + ctrl (cutoffs default 0 = keep-all)
  k_anchor     <<<N_ANCH / 256, 256, 0, stream>>>(gt, labels, targets, hp, hn);
  k_gtbest_sep <<<NG, 256, 0, stream>>>(gt, labels, hp, hn);
  k_findbin    <<<1, 1024, 0, stream>>>(hp, hn, ctrl);
  k_collect    <<<N_ANCH / 256, 256, 0, stream>>>(labels, ctrl, cp, cn);
  k_cutoff     <<<1, 1024, 0, stream>>>(ctrl, cp, cn);
  k_apply      <<<N_ANCH / 256, 256, 0, stream>>>(labels, meta, ctrl);
}